// Round 6
// baseline (262.630 us; speedup 1.0000x reference)
//
#include <hip/hip_runtime.h>
#include <hip/hip_bf16.h>
#include <math.h>

#define T_SEQ   2048
#define D_MOD   1024
#define N_HEADS 16
#define HEAD_DIM 64
#define B_BATCH 2
#define M_ROWS  (B_BATCH * T_SEQ)   // 4096

typedef unsigned short u16;
typedef unsigned int u32;
typedef __attribute__((ext_vector_type(8))) short short8;
typedef __attribute__((ext_vector_type(4))) float floatx4;
typedef __attribute__((ext_vector_type(16))) float f32x16;
typedef __attribute__((ext_vector_type(4))) u32 u32x4;

__device__ inline floatx4 mfma16(short8 a, short8 b, floatx4 c) {
  return __builtin_amdgcn_mfma_f32_16x16x32_bf16(a, b, c, 0, 0, 0);
}
__device__ inline f32x16 mfma32(short8 a, short8 b, f32x16 c) {
  return __builtin_amdgcn_mfma_f32_32x32x16_bf16(a, b, c, 0, 0, 0);
}

__device__ inline u16 f2bf(float f) {
  __hip_bfloat16 h = __float2bfloat16(f);   // RNE
  return __builtin_bit_cast(u16, h);
}
__device__ inline u32 pack2bf(float lo, float hi) {
  return (u32)f2bf(lo) | ((u32)f2bf(hi) << 16);
}

// async global -> LDS, 16B per lane; dest = uniform base + lane*16
__device__ inline void gload16(const void* g, void* s) {
  __builtin_amdgcn_global_load_lds(
      (const __attribute__((address_space(1))) void*)g,
      (__attribute__((address_space(3))) void*)s, 16, 0, 0);
}

// ---------------------------------------------------------------- fused casts
__global__ void cast_all_kernel(const float* __restrict__ x,
                                const float* __restrict__ Wq, const float* __restrict__ Wk,
                                const float* __restrict__ Wv, const float* __restrict__ Wo,
                                u16* __restrict__ Xb, u16* __restrict__ Wqb, u16* __restrict__ Wkb,
                                u16* __restrict__ Wvb, u16* __restrict__ Wob) {
  size_t i4 = ((size_t)blockIdx.x * 256 + threadIdx.x) * 4;
  size_t seg = i4 >> 20;
  const float* src; u16* dst; size_t off;
  if (seg < 4)       { src = x;  dst = Xb;  off = i4; }
  else if (seg == 4) { src = Wq; dst = Wqb; off = i4 - ((size_t)4 << 20); }
  else if (seg == 5) { src = Wk; dst = Wkb; off = i4 - ((size_t)5 << 20); }
  else if (seg == 6) { src = Wv; dst = Wvb; off = i4 - ((size_t)6 << 20); }
  else               { src = Wo; dst = Wob; off = i4 - ((size_t)7 << 20); }
  float4 v = *(const float4*)(src + off);
  ushort4 o;
  o.x = f2bf(v.x); o.y = f2bf(v.y); o.z = f2bf(v.z); o.w = f2bf(v.w);
  *(ushort4*)(dst + off) = o;
}

// ---------------------------------------------------------------- rope table
__global__ void rope_table_kernel(float* __restrict__ cosT, float* __restrict__ sinT) {
  int tid = blockIdx.x * blockDim.x + threadIdx.x;   // T*32
  int t = tid >> 5, j = tid & 31;
  double inv = pow(10000.0, -((double)(2 * j) / 64.0));
  double a = (double)t * inv;
  cosT[tid] = (float)cos(a);
  sinT[tid] = (float)sin(a);
}

// ---------------------------------------------------------------- GEMM: C[M,N] = A[M,K] * W[N,K]^T + bias
// 128x128 tile, BK=32, double-buffered LDS via global_load_lds(16B), 4 waves (2x2).
// DO_ROPE: z<2 -> fused RoPE epilogue (Q,K); z==2 -> V^T epilogue (writes [B,H,64,T]).
template<int OUT_BF16, int DO_ROPE>
__global__ __launch_bounds__(256) void gemm128_kernel(
    const u16* __restrict__ A,
    const u16* __restrict__ W0, const u16* __restrict__ W1, const u16* __restrict__ W2,
    const float* __restrict__ b0, const float* __restrict__ b1, const float* __restrict__ b2,
    void* __restrict__ C0, void* __restrict__ C1, void* __restrict__ C2,
    const float* __restrict__ cosT, const float* __restrict__ sinT) {
  const int z = blockIdx.z;
  const u16*  W    = (z == 0) ? W0 : (z == 1 ? W1 : W2);
  const float* bias = (z == 0) ? b0 : (z == 1 ? b1 : b2);
  void*       C    = (z == 0) ? C0 : (z == 1 ? C1 : C2);
  const int K = D_MOD, N = D_MOD;

  __shared__ __align__(16) char smem[34816];
  u16* lA0 = (u16*)smem;                 // [128*32]
  u16* lA1 = (u16*)(smem + 8192);
  u16* lB0 = (u16*)(smem + 16384);
  u16* lB1 = (u16*)(smem + 24576);

  const int tid = threadIdx.x;
  const int w = tid >> 6, l = tid & 63, g = l >> 4, ln = l & 15;
  const int wr = w >> 1, wc = w & 1;
  const int m0 = blockIdx.y * 128, n0 = blockIdx.x * 128;

  floatx4 acc[4][4];
#pragma unroll
  for (int mi = 0; mi < 4; ++mi)
#pragma unroll
    for (int ni = 0; ni < 4; ++ni) acc[mi][ni] = (floatx4){0.f, 0.f, 0.f, 0.f};

  auto stage = [&](u16* la, u16* lb, int kk) {
#pragma unroll
    for (int p = 0; p < 2; ++p) {
      int c = p * 256 + w * 64 + l;
      int r = c >> 2, cc = c & 3;
      gload16(A + (size_t)(m0 + r) * K + kk + cc * 8, la + (p * 256 + w * 64) * 8);
      gload16(W + (size_t)(n0 + r) * K + kk + cc * 8, lb + (p * 256 + w * 64) * 8);
    }
  };

  stage(lA0, lB0, 0);
  __syncthreads();
  for (int t = 0; t < K / 32; ++t) {
    u16* la = (t & 1) ? lA1 : lA0;
    u16* lb = (t & 1) ? lB1 : lB0;
    if (t + 1 < K / 32) stage((t & 1) ? lA0 : lA1, (t & 1) ? lB0 : lB1, (t + 1) * 32);
    short8 af[4], bf[4];
#pragma unroll
    for (int mi = 0; mi < 4; ++mi)
      af[mi] = *(const short8*)&la[(wr * 64 + mi * 16 + ln) * 32 + g * 8];
#pragma unroll
    for (int ni = 0; ni < 4; ++ni)
      bf[ni] = *(const short8*)&lb[(wc * 64 + ni * 16 + ln) * 32 + g * 8];
#pragma unroll
    for (int mi = 0; mi < 4; ++mi)
#pragma unroll
      for (int ni = 0; ni < 4; ++ni)
        acc[mi][ni] = mfma16(af[mi], bf[ni], acc[mi][ni]);
    __syncthreads();
  }

  float bv[4];
#pragma unroll
  for (int ni = 0; ni < 4; ++ni) bv[ni] = bias[n0 + wc * 64 + ni * 16 + ln];

  if (DO_ROPE && z == 2) {
    // ---- V^T epilogue: bounce C-tile through LDS, write Vt[B,H,64,T]
    u16* pt = (u16*)smem;   // [128][136] u16
#pragma unroll
    for (int mi = 0; mi < 4; ++mi)
#pragma unroll
      for (int ni = 0; ni < 4; ++ni)
#pragma unroll
        for (int r = 0; r < 4; ++r)
          pt[(wc * 64 + ni * 16 + ln) * 136 + wr * 64 + mi * 16 + g * 4 + r] =
              f2bf(acc[mi][ni][r] + bv[ni]);
    __syncthreads();
    u16* Vt = (u16*)C;
    const int b = m0 >> 11, tc0 = m0 & (T_SEQ - 1);
#pragma unroll
    for (int i = 0; i < 8; ++i) {
      const int c = tid + 256 * i;
      const int row = c >> 4, mc = c & 15;
      const int n = n0 + row;
      const int hh = n >> 6, d = n & 63;
      short8 val = *(const short8*)&pt[row * 136 + mc * 8];
      *(short8*)(Vt + ((size_t)(b * N_HEADS + hh) * 64 + d) * T_SEQ + tc0 + mc * 8) = val;
    }
    return;
  }

#pragma unroll
  for (int mi = 0; mi < 4; ++mi) {
#pragma unroll
    for (int r = 0; r < 4; ++r) {
      const int m = m0 + wr * 64 + mi * 16 + g * 4 + r;
      if (DO_ROPE && z < 2) {
        const int t = m & (T_SEQ - 1);
#pragma unroll
        for (int ni = 0; ni < 2; ++ni) {
          const int j = ni * 16 + ln;
          float cv = cosT[t * 32 + j], sv = sinT[t * 32 + j];
          float v1 = acc[mi][ni][r] + bv[ni];
          float v2 = acc[mi][ni + 2][r] + bv[ni + 2];
          ((u16*)C)[(size_t)m * N + n0 + wc * 64 + j]      = f2bf(v1 * cv - v2 * sv);
          ((u16*)C)[(size_t)m * N + n0 + wc * 64 + j + 32] = f2bf(v1 * sv + v2 * cv);
        }
      } else {
#pragma unroll
        for (int ni = 0; ni < 4; ++ni) {
          float v = acc[mi][ni][r] + bv[ni];
          size_t idx = (size_t)m * N + n0 + wc * 64 + ni * 16 + ln;
          if (OUT_BF16) ((u16*)C)[idx] = f2bf(v);
          else          ((float*)C)[idx] = v;
        }
      }
    }
  }
}

// ---------------------------------------------------------------- flash attention v6 (causal)
// Swapped-operand 32x32x16, in-register softmax, per-lane scalar m/l (as v5), PLUS:
// K reg-double-buffered prefetch, V single-buffer issued early (V before K-prefetch so
// PV's vmcnt wait never drains the K-prefetch), peeled masked last tile w/ even-qt
// half-skip, balanced waves (qt = 4*qg + w), heavy blocks dispatched first.
__global__ __launch_bounds__(256) void flash6_kernel(const u16* __restrict__ Q, const u16* __restrict__ Kb,
                                                     const u16* __restrict__ Vt, u16* __restrict__ O) {
  const int tid = threadIdx.x;
  const int w = tid >> 6, l = tid & 63;
  const int lq = l & 31, hi = l >> 5;

  // XCD-clustered: 64 consecutive wgs per XCD -> 4 bh per XCD (K+Vt ~2MB in 4MB L2)
  const int orig = blockIdx.x;                    // 0..511
  const int wg = (orig & 7) * 64 + (orig >> 3);
  const int bh = wg >> 4;                         // 0..31
  const int qg = wg & 15;                         // 0..15
  const int qt = (15 - qg) * 4 + w;               // heavy q-tiles first; block spread = 1 tile
  const int q0 = qt * 32;
  const int b = bh >> 4, h = bh & 15;

  const u16* Qh = Q  + (size_t)b * T_SEQ * D_MOD + h * HEAD_DIM;
  const u16* Kh = Kb + (size_t)b * T_SEQ * D_MOD + h * HEAD_DIM;
  const u16* Vh = Vt + (size_t)bh * 64 * T_SEQ;   // rows d, stride T_SEQ

  // Q fragments (B-operand: col = q0+lq, k-elems d = 16j + 8hi + 0..7)
  short8 qf[4];
  {
    const u16* qp = Qh + (size_t)(q0 + lq) * D_MOD + 8 * hi;
#pragma unroll
    for (int j = 0; j < 4; ++j) qf[j] = *(const short8*)(qp + 16 * j);
  }

  f32x16 o0, o1;
#pragma unroll
  for (int r = 0; r < 16; ++r) { o0[r] = 0.f; o1[r] = 0.f; }
  float m_r = -INFINITY, l_r = 0.f;

  short8 kf0A[4], kf1A[4], kf0B[4], kf1B[4], vf0[4], vf1[4];

#define PREF_K(KF0, KF1, K0) { \
  const u16* kp0_ = Kh + (size_t)((K0) + lq) * D_MOD + 8 * hi; \
  const u16* kp1_ = kp0_ + 32 * D_MOD; \
  _Pragma("unroll") for (int j_ = 0; j_ < 4; ++j_) { \
    KF0[j_] = *(const short8*)(kp0_ + 16 * j_); \
    KF1[j_] = *(const short8*)(kp1_ + 16 * j_); } }

#define PREF_V(K0) { \
  const u16* vp0_ = Vh + (size_t)lq * T_SEQ + (K0) + 8 * hi; \
  const u16* vp1_ = vp0_ + 32 * T_SEQ; \
  _Pragma("unroll") for (int j_ = 0; j_ < 4; ++j_) { \
    vf0[j_] = *(const short8*)(vp0_ + 16 * j_); \
    vf1[j_] = *(const short8*)(vp1_ + 16 * j_); } }

// full unmasked tile from (KF0,KF1) + vf0/vf1
#define TILE_FULL(KF0, KF1) { \
  f32x16 s0_, s1_; \
  _Pragma("unroll") for (int r_ = 0; r_ < 16; ++r_) { s0_[r_] = 0.f; s1_[r_] = 0.f; } \
  __builtin_amdgcn_s_setprio(1); \
  _Pragma("unroll") for (int j_ = 0; j_ < 4; ++j_) { \
    s0_ = mfma32(KF0[j_], qf[j_], s0_); \
    s1_ = mfma32(KF1[j_], qf[j_], s1_); } \
  __builtin_amdgcn_s_setprio(0); \
  float p_[32]; \
  _Pragma("unroll") for (int r_ = 0; r_ < 16; ++r_) { \
    p_[r_] = s0_[r_] * 0.125f; p_[16 + r_] = s1_[r_] * 0.125f; } \
  float mx_ = p_[0]; \
  _Pragma("unroll") for (int i_ = 1; i_ < 32; ++i_) mx_ = fmaxf(mx_, p_[i_]); \
  mx_ = fmaxf(mx_, __shfl_xor(mx_, 32)); \
  const float mnew_ = fmaxf(m_r, mx_); \
  const float alpha_ = __expf(m_r - mnew_); \
  l_r *= alpha_; \
  _Pragma("unroll") for (int r_ = 0; r_ < 16; ++r_) { o0[r_] *= alpha_; o1[r_] *= alpha_; } \
  m_r = mnew_; \
  _Pragma("unroll") for (int i_ = 0; i_ < 32; ++i_) p_[i_] = __expf(p_[i_] - m_r); \
  float sum_ = 0.f; \
  _Pragma("unroll") for (int i_ = 0; i_ < 32; ++i_) sum_ += p_[i_]; \
  sum_ += __shfl_xor(sum_, 32); \
  l_r += sum_; \
  u32x4 fw_[4]; \
  _Pragma("unroll") for (int a_ = 0; a_ < 2; ++a_) { \
    u32 W_[8]; \
    _Pragma("unroll") for (int j_ = 0; j_ < 8; ++j_) \
      W_[j_] = pack2bf(p_[16 * a_ + 2 * j_], p_[16 * a_ + 2 * j_ + 1]); \
    u32 A0_ = __shfl_xor(hi ? W_[0] : W_[2], 32); \
    u32 A1_ = __shfl_xor(hi ? W_[1] : W_[3], 32); \
    u32 B0_ = __shfl_xor(hi ? W_[4] : W_[6], 32); \
    u32 B1_ = __shfl_xor(hi ? W_[5] : W_[7], 32); \
    fw_[2 * a_]     = (u32x4){hi ? A0_ : W_[0], hi ? A1_ : W_[1], hi ? W_[2] : A0_, hi ? W_[3] : A1_}; \
    fw_[2 * a_ + 1] = (u32x4){hi ? B0_ : W_[4], hi ? B1_ : W_[5], hi ? W_[6] : B0_, hi ? W_[7] : B1_}; } \
  __builtin_amdgcn_s_setprio(1); \
  _Pragma("unroll") for (int j_ = 0; j_ < 4; ++j_) { \
    short8 pf_ = __builtin_bit_cast(short8, fw_[j_]); \
    o0 = mfma32(vf0[j_], pf_, o0); \
    o1 = mfma32(vf1[j_], pf_, o1); } \
  __builtin_amdgcn_s_setprio(0); }

// peeled last tile (masked). even qt: second kv-half fully masked -> skipped entirely.
#define TILE_LAST(KF0, KF1, K0L) { \
  const int qrow_ = q0 + lq; \
  f32x16 s0_; \
  _Pragma("unroll") for (int r_ = 0; r_ < 16; ++r_) s0_[r_] = 0.f; \
  __builtin_amdgcn_s_setprio(1); \
  _Pragma("unroll") for (int j_ = 0; j_ < 4; ++j_) s0_ = mfma32(KF0[j_], qf[j_], s0_); \
  __builtin_amdgcn_s_setprio(0); \
  if ((qt & 1) == 0) { \
    float p_[16]; \
    _Pragma("unroll") for (int r_ = 0; r_ < 16; ++r_) { \
      const int kv_ = (K0L) + (r_ & 3) + 8 * (r_ >> 2) + 4 * hi; \
      p_[r_] = (kv_ > qrow_) ? -10000.0f : s0_[r_] * 0.125f; } \
    float mx_ = p_[0]; \
    _Pragma("unroll") for (int i_ = 1; i_ < 16; ++i_) mx_ = fmaxf(mx_, p_[i_]); \
    mx_ = fmaxf(mx_, __shfl_xor(mx_, 32)); \
    const float mnew_ = fmaxf(m_r, mx_); \
    const float alpha_ = __expf(m_r - mnew_); \
    l_r *= alpha_; \
    _Pragma("unroll") for (int r_ = 0; r_ < 16; ++r_) { o0[r_] *= alpha_; o1[r_] *= alpha_; } \
    m_r = mnew_; \
    _Pragma("unroll") for (int i_ = 0; i_ < 16; ++i_) p_[i_] = __expf(p_[i_] - m_r); \
    float sum_ = 0.f; \
    _Pragma("unroll") for (int i_ = 0; i_ < 16; ++i_) sum_ += p_[i_]; \
    sum_ += __shfl_xor(sum_, 32); \
    l_r += sum_; \
    u32x4 fw_[2]; \
    { u32 W_[8]; \
      _Pragma("unroll") for (int j_ = 0; j_ < 8; ++j_) W_[j_] = pack2bf(p_[2 * j_], p_[2 * j_ + 1]); \
      u32 A0_ = __shfl_xor(hi ? W_[0] : W_[2], 32); \
      u32 A1_ = __shfl_xor(hi ? W_[1] : W_[3], 32); \
      u32 B0_ = __shfl_xor(hi ? W_[4] : W_[6], 32); \
      u32 B1_ = __shfl_xor(hi ? W_[5] : W_[7], 32); \
      fw_[0] = (u32x4){hi ? A0_ : W_[0], hi ? A1_ : W_[1], hi ? W_[2] : A0_, hi ? W_[3] : A1_}; \
      fw_[1] = (u32x4){hi ? B0_ : W_[4], hi ? B1_ : W_[5], hi ? W_[6] : B0_, hi ? W_[7] : B1_}; } \
    __builtin_amdgcn_s_setprio(1); \
    _Pragma("unroll") for (int j_ = 0; j_ < 2; ++j_) { \
      short8 pf_ = __builtin_bit_cast(short8, fw_[j_]); \
      o0 = mfma32(vf0[j_], pf_, o0); \
      o1 = mfma32(vf1[j_], pf_, o1); } \
    __builtin_amdgcn_s_setprio(0); \
  } else { \
    f32x16 s1_; \
    _Pragma("unroll") for (int r_ = 0; r_ < 16; ++r_) s1_[r_] = 0.f; \
    __builtin_amdgcn_s_setprio(1); \
    _Pragma("unroll") for (int j_ = 0; j_ < 4; ++j_) s1_ = mfma32(KF1[j_], qf[j_], s1_); \
    __builtin_amdgcn_s_setprio(0); \
    float p_[32]; \
    _Pragma("unroll") for (int r_ = 0; r_ < 16; ++r_) { \
      p_[r_] = s0_[r_] * 0.125f; \
      const int kv_ = (K0L) + 32 + (r_ & 3) + 8 * (r_ >> 2) + 4 * hi; \
      p_[16 + r_] = (kv_ > qrow_) ? -10000.0f : s1_[r_] * 0.125f; } \
    float mx_ = p_[0]; \
    _Pragma("unroll") for (int i_ = 1; i_ < 32; ++i_) mx_ = fmaxf(mx_, p_[i_]); \
    mx_ = fmaxf(mx_, __shfl_xor(mx_, 32)); \
    const float mnew_ = fmaxf(m_r, mx_); \
    const float alpha_ = __expf(m_r - mnew_); \
    l_r *= alpha_; \
    _Pragma("unroll") for (int r_ = 0; r_ < 16; ++r_) { o0[r_] *= alpha_; o1[r_] *= alpha_; } \
    m_r = mnew_; \
    _Pragma("unroll") for (int i_ = 0; i_ < 32; ++i_) p_[i_] = __expf(p_[i_] - m_r); \
    float sum_ = 0.f; \
    _Pragma("unroll") for (int i_ = 0; i_ < 32; ++i_) sum_ += p_[i_]; \
    sum_ += __shfl_xor(sum_, 32); \
    l_r += sum_; \
    u32x4 fw_[4]; \
    _Pragma("unroll") for (int a_ = 0; a_ < 2; ++a_) { \
      u32 W_[8]; \
      _Pragma("unroll") for (int j_ = 0; j_ < 8; ++j_) \
        W_[j_] = pack2bf(p_[16 * a_ + 2 * j_], p_[16 * a_ + 2 * j_ + 1]); \
      u32 A0_ = __shfl_xor(hi ? W_[0] : W_[2], 32); \
      u32 A1_ = __shfl_xor(hi ? W_[1] : W_[3], 32); \
      u32 B0_ = __shfl_xor(hi ? W_[4] : W_[6], 32); \
      u32 B1_ = __shfl_xor(hi ? W_[5] : W_[7], 32); \
      fw_[2 * a_]     = (u32x4){hi ? A0_ : W_[0], hi ? A1_ : W_[1], hi ? W_[2] : A0_, hi ? W_[3] : A1_}; \
      fw_[2 * a_ + 1] = (u32x4){hi ? B0_ : W_[4], hi ? B1_ : W_[5], hi ? W_[6] : B0_, hi ? W_[7] : B1_}; } \
    __builtin_amdgcn_s_setprio(1); \
    _Pragma("unroll") for (int j_ = 0; j_ < 4; ++j_) { \
      short8 pf_ = __builtin_bit_cast(short8, fw_[j_]); \
      o0 = mfma32(vf0[j_], pf_, o0); \
      o1 = mfma32(vf1[j_], pf_, o1); } \
    __builtin_amdgcn_s_setprio(0); } }

  const int ntiles = (qt >> 1) + 1;
  PREF_K(kf0A, kf1A, 0);
  int t = 0;
  while (t + 1 < ntiles) {
    PREF_V(t * 64);                         // V(t) before K(t+1): PV waits vmcnt(8) only
    PREF_K(kf0B, kf1B, (t + 1) * 64);
    TILE_FULL(kf0A, kf1A);
    ++t;
    if (t + 1 >= ntiles) {
      PREF_V(t * 64);
      TILE_LAST(kf0B, kf1B, t * 64);
      goto flash_done;
    }
    PREF_V(t * 64);
    PREF_K(kf0A, kf1A, (t + 1) * 64);
    TILE_FULL(kf0B, kf1B);
    ++t;
  }
  PREF_V(t * 64);
  TILE_LAST(kf0A, kf1A, t * 64);
flash_done:;

  // ---- epilogue: per-lane scalar 1/l, write O[b][q][h*64+d]
  const float inv = 1.0f / l_r;
  u16* op = O + (size_t)b * T_SEQ * D_MOD + (size_t)(q0 + lq) * D_MOD + h * HEAD_DIM;
#pragma unroll
  for (int a = 0; a < 2; ++a) {
#pragma unroll
    for (int rq = 0; rq < 4; ++rq) {
      const int d0 = 32 * a + 8 * rq + 4 * hi;
      ushort4 st;
      st.x = f2bf(((a == 0) ? o0[4 * rq + 0] : o1[4 * rq + 0]) * inv);
      st.y = f2bf(((a == 0) ? o0[4 * rq + 1] : o1[4 * rq + 1]) * inv);
      st.z = f2bf(((a == 0) ? o0[4 * rq + 2] : o1[4 * rq + 2]) * inv);
      st.w = f2bf(((a == 0) ? o0[4 * rq + 3] : o1[4 * rq + 3]) * inv);
      *(ushort4*)(op + d0) = st;
    }
  }
}

// ---------------------------------------------------------------- launch
extern "C" void kernel_launch(void* const* d_in, const int* in_sizes, int n_in,
                              void* d_out, int out_size, void* d_ws, size_t ws_size,
                              hipStream_t stream) {
  const float* x  = (const float*)d_in[0];
  const float* Wq = (const float*)d_in[2];
  const float* bq = (const float*)d_in[3];
  const float* Wk = (const float*)d_in[4];
  const float* bk = (const float*)d_in[5];
  const float* Wv = (const float*)d_in[6];
  const float* bv = (const float*)d_in[7];
  const float* Wo = (const float*)d_in[8];
  const float* bo = (const float*)d_in[9];
  float* out = (float*)d_out;

  char* ws = (char*)d_ws;
  const size_t MB = 1024 * 1024;
  u16* Xb   = (u16*)(ws + 0);          // 8 MB; dead after QKV gemm -> Ab reuses it
  u16* Ab   = (u16*)(ws + 0);
  u16* Wqb  = (u16*)(ws + 8 * MB);
  u16* Wkb  = (u16*)(ws + 10 * MB);
  u16* Wvb  = (u16*)(ws + 12 * MB);
  u16* Wob  = (u16*)(ws + 14 * MB);
  u16* Qb   = (u16*)(ws + 16 * MB);    // 8 MB
  u16* Kb   = (u16*)(ws + 24 * MB);    // 8 MB
  u16* Vt   = (u16*)(ws + 32 * MB);    // 16 MB  [B,H,64,T]
  float* cosT = (float*)(ws + 48 * MB);          // 256 KB
  float* sinT = (float*)(ws + 48 * MB + 256 * 1024);

  cast_all_kernel<<<8192, 256, 0, stream>>>(x, Wq, Wk, Wv, Wo, Xb, Wqb, Wkb, Wvb, Wob);
  rope_table_kernel<<<256, 256, 0, stream>>>(cosT, sinT);

  gemm128_kernel<1, 1><<<dim3(8, 32, 3), 256, 0, stream>>>(
      Xb, Wqb, Wkb, Wvb, bq, bk, bv, Qb, Kb, Vt, cosT, sinT);

  flash6_kernel<<<dim3(512), 256, 0, stream>>>(Qb, Kb, Vt, Ab);

  gemm128_kernel<0, 0><<<dim3(8, 32, 1), 256, 0, stream>>>(
      Ab, Wob, Wob, Wob, bo, bo, bo, out, out, out, nullptr, nullptr);
}

// Round 7
// 238.277 us; speedup vs baseline: 1.1022x; 1.1022x over previous
//
#include <hip/hip_runtime.h>
#include <hip/hip_bf16.h>
#include <math.h>

#define T_SEQ   2048
#define D_MOD   1024
#define N_HEADS 16
#define HEAD_DIM 64
#define B_BATCH 2
#define M_ROWS  (B_BATCH * T_SEQ)   // 4096

typedef unsigned short u16;
typedef unsigned int u32;
typedef __attribute__((ext_vector_type(8))) short short8;
typedef __attribute__((ext_vector_type(4))) float floatx4;
typedef __attribute__((ext_vector_type(16))) float f32x16;
typedef __attribute__((ext_vector_type(4))) u32 u32x4;

__device__ inline floatx4 mfma16(short8 a, short8 b, floatx4 c) {
  return __builtin_amdgcn_mfma_f32_16x16x32_bf16(a, b, c, 0, 0, 0);
}
__device__ inline f32x16 mfma32(short8 a, short8 b, f32x16 c) {
  return __builtin_amdgcn_mfma_f32_32x32x16_bf16(a, b, c, 0, 0, 0);
}

__device__ inline u16 f2bf(float f) {
  __hip_bfloat16 h = __float2bfloat16(f);   // RNE
  return __builtin_bit_cast(u16, h);
}
__device__ inline u32 pack2bf(float lo, float hi) {
  return (u32)f2bf(lo) | ((u32)f2bf(hi) << 16);
}

// async global -> LDS, 16B per lane; dest = uniform base + lane*16
__device__ inline void gload16(const void* g, void* s) {
  __builtin_amdgcn_global_load_lds(
      (const __attribute__((address_space(1))) void*)g,
      (__attribute__((address_space(3))) void*)s, 16, 0, 0);
}

// ---------------------------------------------------------------- fused casts
__global__ void cast_all_kernel(const float* __restrict__ x,
                                const float* __restrict__ Wq, const float* __restrict__ Wk,
                                const float* __restrict__ Wv, const float* __restrict__ Wo,
                                u16* __restrict__ Xb, u16* __restrict__ Wqb, u16* __restrict__ Wkb,
                                u16* __restrict__ Wvb, u16* __restrict__ Wob) {
  size_t i4 = ((size_t)blockIdx.x * 256 + threadIdx.x) * 4;
  size_t seg = i4 >> 20;
  const float* src; u16* dst; size_t off;
  if (seg < 4)       { src = x;  dst = Xb;  off = i4; }
  else if (seg == 4) { src = Wq; dst = Wqb; off = i4 - ((size_t)4 << 20); }
  else if (seg == 5) { src = Wk; dst = Wkb; off = i4 - ((size_t)5 << 20); }
  else if (seg == 6) { src = Wv; dst = Wvb; off = i4 - ((size_t)6 << 20); }
  else               { src = Wo; dst = Wob; off = i4 - ((size_t)7 << 20); }
  float4 v = *(const float4*)(src + off);
  ushort4 o;
  o.x = f2bf(v.x); o.y = f2bf(v.y); o.z = f2bf(v.z); o.w = f2bf(v.w);
  *(ushort4*)(dst + off) = o;
}

// ---------------------------------------------------------------- rope table
__global__ void rope_table_kernel(float* __restrict__ cosT, float* __restrict__ sinT) {
  int tid = blockIdx.x * blockDim.x + threadIdx.x;   // T*32
  int t = tid >> 5, j = tid & 31;
  double inv = pow(10000.0, -((double)(2 * j) / 64.0));
  double a = (double)t * inv;
  cosT[tid] = (float)cos(a);
  sinT[tid] = (float)sin(a);
}

// ---------------------------------------------------------------- GEMM: C[M,N] = A[M,K] * W[N,K]^T + bias
// 128x128 tile, BK=32, double-buffered LDS via global_load_lds(16B), 4 waves (2x2).
// DO_ROPE: z<2 -> fused RoPE epilogue (Q,K); z==2 -> V^T epilogue (writes [B,H,64,T]).
template<int OUT_BF16, int DO_ROPE>
__global__ __launch_bounds__(256) void gemm128_kernel(
    const u16* __restrict__ A,
    const u16* __restrict__ W0, const u16* __restrict__ W1, const u16* __restrict__ W2,
    const float* __restrict__ b0, const float* __restrict__ b1, const float* __restrict__ b2,
    void* __restrict__ C0, void* __restrict__ C1, void* __restrict__ C2,
    const float* __restrict__ cosT, const float* __restrict__ sinT) {
  const int z = blockIdx.z;
  const u16*  W    = (z == 0) ? W0 : (z == 1 ? W1 : W2);
  const float* bias = (z == 0) ? b0 : (z == 1 ? b1 : b2);
  void*       C    = (z == 0) ? C0 : (z == 1 ? C1 : C2);
  const int K = D_MOD, N = D_MOD;

  __shared__ __align__(16) char smem[34816];
  u16* lA0 = (u16*)smem;                 // [128*32]
  u16* lA1 = (u16*)(smem + 8192);
  u16* lB0 = (u16*)(smem + 16384);
  u16* lB1 = (u16*)(smem + 24576);

  const int tid = threadIdx.x;
  const int w = tid >> 6, l = tid & 63, g = l >> 4, ln = l & 15;
  const int wr = w >> 1, wc = w & 1;
  const int m0 = blockIdx.y * 128, n0 = blockIdx.x * 128;

  floatx4 acc[4][4];
#pragma unroll
  for (int mi = 0; mi < 4; ++mi)
#pragma unroll
    for (int ni = 0; ni < 4; ++ni) acc[mi][ni] = (floatx4){0.f, 0.f, 0.f, 0.f};

  auto stage = [&](u16* la, u16* lb, int kk) {
#pragma unroll
    for (int p = 0; p < 2; ++p) {
      int c = p * 256 + w * 64 + l;
      int r = c >> 2, cc = c & 3;
      gload16(A + (size_t)(m0 + r) * K + kk + cc * 8, la + (p * 256 + w * 64) * 8);
      gload16(W + (size_t)(n0 + r) * K + kk + cc * 8, lb + (p * 256 + w * 64) * 8);
    }
  };

  stage(lA0, lB0, 0);
  __syncthreads();
  for (int t = 0; t < K / 32; ++t) {
    u16* la = (t & 1) ? lA1 : lA0;
    u16* lb = (t & 1) ? lB1 : lB0;
    if (t + 1 < K / 32) stage((t & 1) ? lA0 : lA1, (t & 1) ? lB0 : lB1, (t + 1) * 32);
    short8 af[4], bf[4];
#pragma unroll
    for (int mi = 0; mi < 4; ++mi)
      af[mi] = *(const short8*)&la[(wr * 64 + mi * 16 + ln) * 32 + g * 8];
#pragma unroll
    for (int ni = 0; ni < 4; ++ni)
      bf[ni] = *(const short8*)&lb[(wc * 64 + ni * 16 + ln) * 32 + g * 8];
#pragma unroll
    for (int mi = 0; mi < 4; ++mi)
#pragma unroll
      for (int ni = 0; ni < 4; ++ni)
        acc[mi][ni] = mfma16(af[mi], bf[ni], acc[mi][ni]);
    __syncthreads();
  }

  float bv[4];
#pragma unroll
  for (int ni = 0; ni < 4; ++ni) bv[ni] = bias[n0 + wc * 64 + ni * 16 + ln];

  if (DO_ROPE && z == 2) {
    // ---- V^T epilogue: bounce C-tile through LDS, write Vt[B,H,64,T]
    u16* pt = (u16*)smem;   // [128][136] u16
#pragma unroll
    for (int mi = 0; mi < 4; ++mi)
#pragma unroll
      for (int ni = 0; ni < 4; ++ni)
#pragma unroll
        for (int r = 0; r < 4; ++r)
          pt[(wc * 64 + ni * 16 + ln) * 136 + wr * 64 + mi * 16 + g * 4 + r] =
              f2bf(acc[mi][ni][r] + bv[ni]);
    __syncthreads();
    u16* Vt = (u16*)C;
    const int b = m0 >> 11, tc0 = m0 & (T_SEQ - 1);
#pragma unroll
    for (int i = 0; i < 8; ++i) {
      const int c = tid + 256 * i;
      const int row = c >> 4, mc = c & 15;
      const int n = n0 + row;
      const int hh = n >> 6, d = n & 63;
      short8 val = *(const short8*)&pt[row * 136 + mc * 8];
      *(short8*)(Vt + ((size_t)(b * N_HEADS + hh) * 64 + d) * T_SEQ + tc0 + mc * 8) = val;
    }
    return;
  }

#pragma unroll
  for (int mi = 0; mi < 4; ++mi) {
#pragma unroll
    for (int r = 0; r < 4; ++r) {
      const int m = m0 + wr * 64 + mi * 16 + g * 4 + r;
      if (DO_ROPE && z < 2) {
        const int t = m & (T_SEQ - 1);
#pragma unroll
        for (int ni = 0; ni < 2; ++ni) {
          const int j = ni * 16 + ln;
          float cv = cosT[t * 32 + j], sv = sinT[t * 32 + j];
          float v1 = acc[mi][ni][r] + bv[ni];
          float v2 = acc[mi][ni + 2][r] + bv[ni + 2];
          ((u16*)C)[(size_t)m * N + n0 + wc * 64 + j]      = f2bf(v1 * cv - v2 * sv);
          ((u16*)C)[(size_t)m * N + n0 + wc * 64 + j + 32] = f2bf(v1 * sv + v2 * cv);
        }
      } else {
#pragma unroll
        for (int ni = 0; ni < 4; ++ni) {
          float v = acc[mi][ni][r] + bv[ni];
          size_t idx = (size_t)m * N + n0 + wc * 64 + ni * 16 + ln;
          if (OUT_BF16) ((u16*)C)[idx] = f2bf(v);
          else          ((float*)C)[idx] = v;
        }
      }
    }
  }
}

// ---------------------------------------------------------------- flash attention v7 (causal, split-KV)
// v5 tile body (proven). One q-tile (32 rows) per block; 4 waves split the KV range
// (t = w, w+4, ...), merged once via LDS (flash split-K rescale). 2048 blocks ->
// 8192 waves (~4-5/SIMD resident). XCD-clustered bh, heavy q-tiles dispatch first.
__global__ __launch_bounds__(256) void flash7_kernel(const u16* __restrict__ Q, const u16* __restrict__ Kb,
                                                     const u16* __restrict__ Vt, u16* __restrict__ O) {
  __shared__ float og[3][32][64];    // partial O of waves 1..3  (24.0 KB)
  __shared__ float mlg[3][2][64];    // partial m,l of waves 1..3 (1.5 KB)

  const int tid = threadIdx.x;
  const int w = tid >> 6, l = tid & 63;
  const int lq = l & 31, hi = l >> 5;

  // XCD-clustered: per XCD 256 consecutive wgs = 4 bh, qt descending (heavy first)
  const int orig = blockIdx.x;                    // 0..2047
  const int wg = (orig & 7) * 256 + (orig >> 3);
  const int bh = wg >> 6;                         // 0..31
  const int qt = 63 - (wg & 63);                  // 0..63
  const int q0 = qt * 32;
  const int b = bh >> 4, h = bh & 15;

  const u16* Qh = Q  + (size_t)b * T_SEQ * D_MOD + h * HEAD_DIM;
  const u16* Kh = Kb + (size_t)b * T_SEQ * D_MOD + h * HEAD_DIM;
  const u16* Vh = Vt + (size_t)bh * 64 * T_SEQ;   // rows d, stride T_SEQ

  // Q fragments (B-operand: col = q0+lq, k-elems d = 16j + 8hi + 0..7)
  short8 qf[4];
  {
    const u16* qp = Qh + (size_t)(q0 + lq) * D_MOD + 8 * hi;
#pragma unroll
    for (int j = 0; j < 4; ++j) qf[j] = *(const short8*)(qp + 16 * j);
  }

  f32x16 o0, o1;
#pragma unroll
  for (int r = 0; r < 16; ++r) { o0[r] = 0.f; o1[r] = 0.f; }
  float m_r = -INFINITY, l_r = 0.f;

  const int ntiles = (qt >> 1) + 1;
  for (int kt = w; kt < ntiles; kt += 4) {
    const int k0 = kt * 64;
    const bool last = (kt == ntiles - 1);

    // ---- issue all 16 loads up-front (K for QK^T, V for PV)
    short8 kf0[4], kf1[4], vf0[4], vf1[4];
    {
      const u16* kp0 = Kh + (size_t)(k0 + lq) * D_MOD + 8 * hi;
      const u16* kp1 = kp0 + 32 * D_MOD;
#pragma unroll
      for (int j = 0; j < 4; ++j) {
        kf0[j] = *(const short8*)(kp0 + 16 * j);
        kf1[j] = *(const short8*)(kp1 + 16 * j);
      }
      const u16* vp0 = Vh + (size_t)lq * T_SEQ + k0 + 8 * hi;
      const u16* vp1 = vp0 + 32 * T_SEQ;
#pragma unroll
      for (int js = 0; js < 4; ++js) {
        vf0[js] = *(const short8*)(vp0 + 16 * js);
        vf1[js] = *(const short8*)(vp1 + 16 * js);
      }
    }

    // ---- S^T = K·Q^T  (two 32-row accs over kv)
    f32x16 s0, s1;
#pragma unroll
    for (int r = 0; r < 16; ++r) { s0[r] = 0.f; s1[r] = 0.f; }
    __builtin_amdgcn_s_setprio(1);
#pragma unroll
    for (int j = 0; j < 4; ++j) {
      s0 = mfma32(kf0[j], qf[j], s0);
      s1 = mfma32(kf1[j], qf[j], s1);
    }
    __builtin_amdgcn_s_setprio(0);

    // ---- scale + causal mask (kv = k0 + 32a + (r&3)+8*(r>>2)+4hi; q = q0+lq)
    float p[32];
#pragma unroll
    for (int r = 0; r < 16; ++r) { p[r] = s0[r] * 0.125f; p[16 + r] = s1[r] * 0.125f; }
    if (last) {
      const int qrow = q0 + lq;
#pragma unroll
      for (int r = 0; r < 16; ++r) {
        const int kv = k0 + (r & 3) + 8 * (r >> 2) + 4 * hi;
        if (kv > qrow) p[r] = -10000.0f;
        if (kv + 32 > qrow) p[16 + r] = -10000.0f;
      }
    }

    // ---- online softmax: local tree + cross-half shfl
    float mx = p[0];
#pragma unroll
    for (int i = 1; i < 32; ++i) mx = fmaxf(mx, p[i]);
    mx = fmaxf(mx, __shfl_xor(mx, 32));

    const float mnew = fmaxf(m_r, mx);
    const float alpha = __expf(m_r - mnew);   // first tile: exp(-inf)=0
    l_r *= alpha;
#pragma unroll
    for (int r = 0; r < 16; ++r) { o0[r] *= alpha; o1[r] *= alpha; }
    m_r = mnew;
#pragma unroll
    for (int i = 0; i < 32; ++i) p[i] = __expf(p[i] - m_r);
    float sum = 0.f;
#pragma unroll
    for (int i = 0; i < 32; ++i) sum += p[i];
    sum += __shfl_xor(sum, 32);
    l_r += sum;

    // ---- P^T fragments: pack pairs to bf16 words, exchange across lane-halves
    u32x4 fw[4];
#pragma unroll
    for (int a = 0; a < 2; ++a) {
      u32 W[8];
#pragma unroll
      for (int j = 0; j < 8; ++j) W[j] = pack2bf(p[16 * a + 2 * j], p[16 * a + 2 * j + 1]);
      // hi=0 needs partner's W0,W1 (for w2,w3); hi=1 needs partner's W2,W3 (for w0,w1)
      u32 A0 = __shfl_xor(hi ? W[0] : W[2], 32);
      u32 A1 = __shfl_xor(hi ? W[1] : W[3], 32);
      u32 B0 = __shfl_xor(hi ? W[4] : W[6], 32);
      u32 B1 = __shfl_xor(hi ? W[5] : W[7], 32);
      fw[2 * a]     = (u32x4){hi ? A0 : W[0], hi ? A1 : W[1], hi ? W[2] : A0, hi ? W[3] : A1};
      fw[2 * a + 1] = (u32x4){hi ? B0 : W[4], hi ? B1 : W[5], hi ? W[6] : B0, hi ? W[7] : B1};
    }

    // ---- O^T += V^T · P^T
    __builtin_amdgcn_s_setprio(1);
#pragma unroll
    for (int js = 0; js < 4; ++js) {
      short8 pf = __builtin_bit_cast(short8, fw[js]);
      o0 = mfma32(vf0[js], pf, o0);
      o1 = mfma32(vf1[js], pf, o1);
    }
    __builtin_amdgcn_s_setprio(0);
  }

  // ---- split-KV merge: waves 1..3 publish partials, wave 0 combines
  if (w > 0) {
    mlg[w - 1][0][l] = m_r;
    mlg[w - 1][1][l] = l_r;
#pragma unroll
    for (int r = 0; r < 16; ++r) {
      og[w - 1][r][l]      = o0[r];
      og[w - 1][16 + r][l] = o1[r];
    }
  }
  __syncthreads();
  if (w != 0) return;

  float m = m_r;
#pragma unroll
  for (int pi = 0; pi < 3; ++pi) m = fmaxf(m, mlg[pi][0][l]);
  const float aS = __expf(m_r - m);          // m finite: wave 0 always owns tile 0
  float lsum = l_r * aS;
#pragma unroll
  for (int r = 0; r < 16; ++r) { o0[r] *= aS; o1[r] *= aS; }
#pragma unroll
  for (int pi = 0; pi < 3; ++pi) {
    const float ap = __expf(mlg[pi][0][l] - m);   // zero-tile partner: exp(-inf-m)=0
    lsum += mlg[pi][1][l] * ap;
#pragma unroll
    for (int r = 0; r < 16; ++r) {
      o0[r] += og[pi][r][l] * ap;
      o1[r] += og[pi][16 + r][l] * ap;
    }
  }

  // ---- epilogue: per-lane scalar 1/l, write O[b][q][h*64+d]
  const float inv = 1.0f / lsum;
  u16* op = O + (size_t)b * T_SEQ * D_MOD + (size_t)(q0 + lq) * D_MOD + h * HEAD_DIM;
#pragma unroll
  for (int a = 0; a < 2; ++a) {
#pragma unroll
    for (int rq = 0; rq < 4; ++rq) {
      const int d0 = 32 * a + 8 * rq + 4 * hi;
      ushort4 st;
      st.x = f2bf(((a == 0) ? o0[4 * rq + 0] : o1[4 * rq + 0]) * inv);
      st.y = f2bf(((a == 0) ? o0[4 * rq + 1] : o1[4 * rq + 1]) * inv);
      st.z = f2bf(((a == 0) ? o0[4 * rq + 2] : o1[4 * rq + 2]) * inv);
      st.w = f2bf(((a == 0) ? o0[4 * rq + 3] : o1[4 * rq + 3]) * inv);
      *(ushort4*)(op + d0) = st;
    }
  }
}

// ---------------------------------------------------------------- launch
extern "C" void kernel_launch(void* const* d_in, const int* in_sizes, int n_in,
                              void* d_out, int out_size, void* d_ws, size_t ws_size,
                              hipStream_t stream) {
  const float* x  = (const float*)d_in[0];
  const float* Wq = (const float*)d_in[2];
  const float* bq = (const float*)d_in[3];
  const float* Wk = (const float*)d_in[4];
  const float* bk = (const float*)d_in[5];
  const float* Wv = (const float*)d_in[6];
  const float* bv = (const float*)d_in[7];
  const float* Wo = (const float*)d_in[8];
  const float* bo = (const float*)d_in[9];
  float* out = (float*)d_out;

  char* ws = (char*)d_ws;
  const size_t MB = 1024 * 1024;
  u16* Xb   = (u16*)(ws + 0);          // 8 MB; dead after QKV gemm -> Ab reuses it
  u16* Ab   = (u16*)(ws + 0);
  u16* Wqb  = (u16*)(ws + 8 * MB);
  u16* Wkb  = (u16*)(ws + 10 * MB);
  u16* Wvb  = (u16*)(ws + 12 * MB);
  u16* Wob  = (u16*)(ws + 14 * MB);
  u16* Qb   = (u16*)(ws + 16 * MB);    // 8 MB
  u16* Kb   = (u16*)(ws + 24 * MB);    // 8 MB
  u16* Vt   = (u16*)(ws + 32 * MB);    // 16 MB  [B,H,64,T]
  float* cosT = (float*)(ws + 48 * MB);          // 256 KB
  float* sinT = (float*)(ws + 48 * MB + 256 * 1024);

  cast_all_kernel<<<8192, 256, 0, stream>>>(x, Wq, Wk, Wv, Wo, Xb, Wqb, Wkb, Wvb, Wob);
  rope_table_kernel<<<256, 256, 0, stream>>>(cosT, sinT);

  gemm128_kernel<1, 1><<<dim3(8, 32, 3), 256, 0, stream>>>(
      Xb, Wqb, Wkb, Wvb, bq, bk, bv, Qb, Kb, Vt, cosT, sinT);

  flash7_kernel<<<dim3(2048), 256, 0, stream>>>(Qb, Kb, Vt, Ab);

  gemm128_kernel<0, 0><<<dim3(8, 32, 1), 256, 0, stream>>>(
      Ab, Wob, Wob, Wob, bo, bo, bo, out, out, out, nullptr, nullptr);
}

// Round 8
// 204.998 us; speedup vs baseline: 1.2811x; 1.1623x over previous
//
#include <hip/hip_runtime.h>
#include <hip/hip_bf16.h>
#include <math.h>

#define T_SEQ   2048
#define D_MOD   1024
#define N_HEADS 16
#define HEAD_DIM 64
#define B_BATCH 2
#define M_ROWS  (B_BATCH * T_SEQ)   // 4096
#define HSLAB   131072               // u16 per (b,h) slab in blocked layouts (8*2048*8)

typedef unsigned short u16;
typedef unsigned int u32;
typedef __attribute__((ext_vector_type(8))) short short8;
typedef __attribute__((ext_vector_type(4))) float floatx4;
typedef __attribute__((ext_vector_type(16))) float f32x16;
typedef __attribute__((ext_vector_type(4))) u32 u32x4;

__device__ inline floatx4 mfma16(short8 a, short8 b, floatx4 c) {
  return __builtin_amdgcn_mfma_f32_16x16x32_bf16(a, b, c, 0, 0, 0);
}
__device__ inline f32x16 mfma32(short8 a, short8 b, f32x16 c) {
  return __builtin_amdgcn_mfma_f32_32x32x16_bf16(a, b, c, 0, 0, 0);
}

__device__ inline u16 f2bf(float f) {
  __hip_bfloat16 h = __float2bfloat16(f);   // RNE
  return __builtin_bit_cast(u16, h);
}
__device__ inline u32 pack2bf(float lo, float hi) {
  return (u32)f2bf(lo) | ((u32)f2bf(hi) << 16);
}

// async global -> LDS, 16B per lane; dest = uniform base + lane*16
__device__ inline void gload16(const void* g, void* s) {
  __builtin_amdgcn_global_load_lds(
      (const __attribute__((address_space(1))) void*)g,
      (__attribute__((address_space(3))) void*)s, 16, 0, 0);
}

// ---------------------------------------------------------------- fused casts
__global__ void cast_all_kernel(const float* __restrict__ x,
                                const float* __restrict__ Wq, const float* __restrict__ Wk,
                                const float* __restrict__ Wv, const float* __restrict__ Wo,
                                u16* __restrict__ Xb, u16* __restrict__ Wqb, u16* __restrict__ Wkb,
                                u16* __restrict__ Wvb, u16* __restrict__ Wob) {
  size_t i4 = ((size_t)blockIdx.x * 256 + threadIdx.x) * 4;
  size_t seg = i4 >> 20;
  const float* src; u16* dst; size_t off;
  if (seg < 4)       { src = x;  dst = Xb;  off = i4; }
  else if (seg == 4) { src = Wq; dst = Wqb; off = i4 - ((size_t)4 << 20); }
  else if (seg == 5) { src = Wk; dst = Wkb; off = i4 - ((size_t)5 << 20); }
  else if (seg == 6) { src = Wv; dst = Wvb; off = i4 - ((size_t)6 << 20); }
  else               { src = Wo; dst = Wob; off = i4 - ((size_t)7 << 20); }
  float4 v = *(const float4*)(src + off);
  ushort4 o;
  o.x = f2bf(v.x); o.y = f2bf(v.y); o.z = f2bf(v.z); o.w = f2bf(v.w);
  *(ushort4*)(dst + off) = o;
}

// ---------------------------------------------------------------- rope table
__global__ void rope_table_kernel(float* __restrict__ cosT, float* __restrict__ sinT) {
  int tid = blockIdx.x * blockDim.x + threadIdx.x;   // T*32
  int t = tid >> 5, j = tid & 31;
  double inv = pow(10000.0, -((double)(2 * j) / 64.0));
  double a = (double)t * inv;
  cosT[tid] = (float)cos(a);
  sinT[tid] = (float)sin(a);
}

// ---------------------------------------------------------------- GEMM: C[M,N] = A[M,K] * W[N,K]^T + bias
// 128x128 tile, BK=32, double-buffered LDS via global_load_lds(16B), 4 waves (2x2).
// DO_ROPE: z<2 -> fused RoPE epilogue writing blocked Qz/Kz[bh][dc][t][8];
//          z==2 -> V^T epilogue writing blocked Vz[bh][kvc][d][8].
template<int OUT_BF16, int DO_ROPE>
__global__ __launch_bounds__(256) void gemm128_kernel(
    const u16* __restrict__ A,
    const u16* __restrict__ W0, const u16* __restrict__ W1, const u16* __restrict__ W2,
    const float* __restrict__ b0, const float* __restrict__ b1, const float* __restrict__ b2,
    void* __restrict__ C0, void* __restrict__ C1, void* __restrict__ C2,
    const float* __restrict__ cosT, const float* __restrict__ sinT) {
  const int z = blockIdx.z;
  const u16*  W    = (z == 0) ? W0 : (z == 1 ? W1 : W2);
  const float* bias = (z == 0) ? b0 : (z == 1 ? b1 : b2);
  void*       C    = (z == 0) ? C0 : (z == 1 ? C1 : C2);
  const int K = D_MOD, N = D_MOD;

  __shared__ __align__(16) char smem[34816];
  u16* lA0 = (u16*)smem;                 // [128*32]
  u16* lA1 = (u16*)(smem + 8192);
  u16* lB0 = (u16*)(smem + 16384);
  u16* lB1 = (u16*)(smem + 24576);

  const int tid = threadIdx.x;
  const int w = tid >> 6, l = tid & 63, g = l >> 4, ln = l & 15;
  const int wr = w >> 1, wc = w & 1;
  const int m0 = blockIdx.y * 128, n0 = blockIdx.x * 128;

  floatx4 acc[4][4];
#pragma unroll
  for (int mi = 0; mi < 4; ++mi)
#pragma unroll
    for (int ni = 0; ni < 4; ++ni) acc[mi][ni] = (floatx4){0.f, 0.f, 0.f, 0.f};

  auto stage = [&](u16* la, u16* lb, int kk) {
#pragma unroll
    for (int p = 0; p < 2; ++p) {
      int c = p * 256 + w * 64 + l;
      int r = c >> 2, cc = c & 3;
      gload16(A + (size_t)(m0 + r) * K + kk + cc * 8, la + (p * 256 + w * 64) * 8);
      gload16(W + (size_t)(n0 + r) * K + kk + cc * 8, lb + (p * 256 + w * 64) * 8);
    }
  };

  stage(lA0, lB0, 0);
  __syncthreads();
  for (int t = 0; t < K / 32; ++t) {
    u16* la = (t & 1) ? lA1 : lA0;
    u16* lb = (t & 1) ? lB1 : lB0;
    if (t + 1 < K / 32) stage((t & 1) ? lA0 : lA1, (t & 1) ? lB0 : lB1, (t + 1) * 32);
    short8 af[4], bf[4];
#pragma unroll
    for (int mi = 0; mi < 4; ++mi)
      af[mi] = *(const short8*)&la[(wr * 64 + mi * 16 + ln) * 32 + g * 8];
#pragma unroll
    for (int ni = 0; ni < 4; ++ni)
      bf[ni] = *(const short8*)&lb[(wc * 64 + ni * 16 + ln) * 32 + g * 8];
#pragma unroll
    for (int mi = 0; mi < 4; ++mi)
#pragma unroll
      for (int ni = 0; ni < 4; ++ni)
        acc[mi][ni] = mfma16(af[mi], bf[ni], acc[mi][ni]);
    __syncthreads();
  }

  float bv[4];
#pragma unroll
  for (int ni = 0; ni < 4; ++ni) bv[ni] = bias[n0 + wc * 64 + ni * 16 + ln];

  if (DO_ROPE && z == 2) {
    // ---- V^T epilogue: bounce C-tile through LDS, write Vz[bh][kvc][d][8]
    u16* pt = (u16*)smem;   // [128][136] u16, row = n_local (head-d), col = m_local (kv)
#pragma unroll
    for (int mi = 0; mi < 4; ++mi)
#pragma unroll
      for (int ni = 0; ni < 4; ++ni)
#pragma unroll
        for (int r = 0; r < 4; ++r)
          pt[(wc * 64 + ni * 16 + ln) * 136 + wr * 64 + mi * 16 + g * 4 + r] =
              f2bf(acc[mi][ni][r] + bv[ni]);
    __syncthreads();
    u16* Vz = (u16*)C;
    const int b = m0 >> 11, tc0 = m0 & (T_SEQ - 1);
#pragma unroll
    for (int i = 0; i < 8; ++i) {
      const int c = tid + 256 * i;        // 0..2047
      const int drow = c & 63;            // d within head
      const int hloc = (c >> 6) & 1;      // which of the 2 heads in this n-block
      const int mc = c >> 7;              // 16B kv-chunk 0..15
      const int bh = b * N_HEADS + ((n0 + hloc * 64) >> 6);
      short8 val = *(const short8*)&pt[(hloc * 64 + drow) * 136 + mc * 8];
      *(short8*)(Vz + (size_t)bh * HSLAB + (size_t)((tc0 >> 3) + mc) * 512 + drow * 8) = val;
    }
    return;
  }

#pragma unroll
  for (int mi = 0; mi < 4; ++mi) {
#pragma unroll
    for (int r = 0; r < 4; ++r) {
      const int m = m0 + wr * 64 + mi * 16 + g * 4 + r;
      if (DO_ROPE && z < 2) {
        // blocked Qz/Kz[bh][dc][t][de] with fused RoPE
        const int t = m & (T_SEQ - 1);
        const int bh = (m >> 11) * N_HEADS + ((n0 + wc * 64) >> 6);
        u16* base = (u16*)C + (size_t)bh * HSLAB + (size_t)t * 8;
#pragma unroll
        for (int ni = 0; ni < 2; ++ni) {
          const int j = ni * 16 + ln;     // d1 = j, d2 = j+32
          float cv = cosT[t * 32 + j], sv = sinT[t * 32 + j];
          float v1 = acc[mi][ni][r] + bv[ni];
          float v2 = acc[mi][ni + 2][r] + bv[ni + 2];
          base[(j >> 3) * 16384 + (j & 7)]       = f2bf(v1 * cv - v2 * sv);
          base[((j >> 3) + 4) * 16384 + (j & 7)] = f2bf(v1 * sv + v2 * cv);
        }
      } else {
#pragma unroll
        for (int ni = 0; ni < 4; ++ni) {
          float v = acc[mi][ni][r] + bv[ni];
          size_t idx = (size_t)m * N + n0 + wc * 64 + ni * 16 + ln;
          if (OUT_BF16) ((u16*)C)[idx] = f2bf(v);
          else          ((float*)C)[idx] = v;
        }
      }
    }
  }
}

// ---------------------------------------------------------------- flash attention v8 (causal, split-KV)
// v5 tile body; blocked K/Q/V layouts -> every fragment load is two contiguous 512B
// runs per instr (ideal L1 line utilization). One q-tile per block, 4 waves split KV,
// LDS merge. XCD-clustered bh, heavy q-tiles first.
__global__ __launch_bounds__(256) void flash8_kernel(const u16* __restrict__ Q, const u16* __restrict__ Kb,
                                                     const u16* __restrict__ Vb, u16* __restrict__ O) {
  __shared__ float og[3][32][64];    // partial O of waves 1..3  (24.0 KB)
  __shared__ float mlg[3][2][64];    // partial m,l of waves 1..3 (1.5 KB)

  const int tid = threadIdx.x;
  const int w = tid >> 6, l = tid & 63;
  const int lq = l & 31, hi = l >> 5;

  // XCD-clustered: per XCD 256 consecutive wgs = 4 bh, qt descending (heavy first)
  const int orig = blockIdx.x;                    // 0..2047
  const int wg = (orig & 7) * 256 + (orig >> 3);
  const int bh = wg >> 6;                         // 0..31
  const int qt = 63 - (wg & 63);                  // 0..63
  const int q0 = qt * 32;
  const int b = bh >> 4, h = bh & 15;

  const u16* Qz = Q  + (size_t)bh * HSLAB;   // [dc=8][t][8]
  const u16* Kz = Kb + (size_t)bh * HSLAB;   // [dc=8][t][8]
  const u16* Vz = Vb + (size_t)bh * HSLAB;   // [kvc=256][d=64][8]

  // Q fragments (B-operand: col = q0+lq, k-elems d = 16j + 8hi + 0..7)
  short8 qf[4];
#pragma unroll
  for (int j = 0; j < 4; ++j)
    qf[j] = *(const short8*)(Qz + (size_t)(2 * j + hi) * 16384 + (q0 + lq) * 8);

  f32x16 o0, o1;
#pragma unroll
  for (int r = 0; r < 16; ++r) { o0[r] = 0.f; o1[r] = 0.f; }
  float m_r = -INFINITY, l_r = 0.f;

  const int ntiles = (qt >> 1) + 1;
  for (int kt = w; kt < ntiles; kt += 4) {
    const int k0 = kt * 64;
    const bool last = (kt == ntiles - 1);

    // ---- issue all 16 loads up-front (K for QK^T, V for PV), all wave-contiguous
    short8 kf0[4], kf1[4], vf0[4], vf1[4];
    {
      const u16* kp = Kz + (size_t)hi * 16384 + (k0 + lq) * 8;
#pragma unroll
      for (int j = 0; j < 4; ++j) {
        kf0[j] = *(const short8*)(kp + (size_t)(2 * j) * 16384);
        kf1[j] = *(const short8*)(kp + (size_t)(2 * j) * 16384 + 256);
      }
      const u16* vp = Vz + (size_t)((k0 >> 3) + hi) * 512 + lq * 8;
#pragma unroll
      for (int js = 0; js < 4; ++js) {
        vf0[js] = *(const short8*)(vp + (size_t)(2 * js) * 512);
        vf1[js] = *(const short8*)(vp + (size_t)(2 * js) * 512 + 256);
      }
    }

    // ---- S^T = K·Q^T  (two 32-row accs over kv)
    f32x16 s0, s1;
#pragma unroll
    for (int r = 0; r < 16; ++r) { s0[r] = 0.f; s1[r] = 0.f; }
    __builtin_amdgcn_s_setprio(1);
#pragma unroll
    for (int j = 0; j < 4; ++j) {
      s0 = mfma32(kf0[j], qf[j], s0);
      s1 = mfma32(kf1[j], qf[j], s1);
    }
    __builtin_amdgcn_s_setprio(0);

    // ---- scale + causal mask (kv = k0 + 32a + (r&3)+8*(r>>2)+4hi; q = q0+lq)
    float p[32];
#pragma unroll
    for (int r = 0; r < 16; ++r) { p[r] = s0[r] * 0.125f; p[16 + r] = s1[r] * 0.125f; }
    if (last) {
      const int qrow = q0 + lq;
#pragma unroll
      for (int r = 0; r < 16; ++r) {
        const int kv = k0 + (r & 3) + 8 * (r >> 2) + 4 * hi;
        if (kv > qrow) p[r] = -10000.0f;
        if (kv + 32 > qrow) p[16 + r] = -10000.0f;
      }
    }

    // ---- online softmax: local tree + cross-half shfl
    float mx = p[0];
#pragma unroll
    for (int i = 1; i < 32; ++i) mx = fmaxf(mx, p[i]);
    mx = fmaxf(mx, __shfl_xor(mx, 32));

    const float mnew = fmaxf(m_r, mx);
    const float alpha = __expf(m_r - mnew);   // first tile: exp(-inf)=0
    l_r *= alpha;
#pragma unroll
    for (int r = 0; r < 16; ++r) { o0[r] *= alpha; o1[r] *= alpha; }
    m_r = mnew;
#pragma unroll
    for (int i = 0; i < 32; ++i) p[i] = __expf(p[i] - m_r);
    float sum = 0.f;
#pragma unroll
    for (int i = 0; i < 32; ++i) sum += p[i];
    sum += __shfl_xor(sum, 32);
    l_r += sum;

    // ---- P^T fragments: pack pairs to bf16 words, exchange across lane-halves
    u32x4 fw[4];
#pragma unroll
    for (int a = 0; a < 2; ++a) {
      u32 W[8];
#pragma unroll
      for (int j = 0; j < 8; ++j) W[j] = pack2bf(p[16 * a + 2 * j], p[16 * a + 2 * j + 1]);
      // hi=0 needs partner's W0,W1 (for w2,w3); hi=1 needs partner's W2,W3 (for w0,w1)
      u32 A0 = __shfl_xor(hi ? W[0] : W[2], 32);
      u32 A1 = __shfl_xor(hi ? W[1] : W[3], 32);
      u32 B0 = __shfl_xor(hi ? W[4] : W[6], 32);
      u32 B1 = __shfl_xor(hi ? W[5] : W[7], 32);
      fw[2 * a]     = (u32x4){hi ? A0 : W[0], hi ? A1 : W[1], hi ? W[2] : A0, hi ? W[3] : A1};
      fw[2 * a + 1] = (u32x4){hi ? B0 : W[4], hi ? B1 : W[5], hi ? W[6] : B0, hi ? W[7] : B1};
    }

    // ---- O^T += V^T · P^T
    __builtin_amdgcn_s_setprio(1);
#pragma unroll
    for (int js = 0; js < 4; ++js) {
      short8 pf = __builtin_bit_cast(short8, fw[js]);
      o0 = mfma32(vf0[js], pf, o0);
      o1 = mfma32(vf1[js], pf, o1);
    }
    __builtin_amdgcn_s_setprio(0);
  }

  // ---- split-KV merge: waves 1..3 publish partials, wave 0 combines
  if (w > 0) {
    mlg[w - 1][0][l] = m_r;
    mlg[w - 1][1][l] = l_r;
#pragma unroll
    for (int r = 0; r < 16; ++r) {
      og[w - 1][r][l]      = o0[r];
      og[w - 1][16 + r][l] = o1[r];
    }
  }
  __syncthreads();
  if (w != 0) return;

  float m = m_r;
#pragma unroll
  for (int pi = 0; pi < 3; ++pi) m = fmaxf(m, mlg[pi][0][l]);
  const float aS = __expf(m_r - m);          // m finite: wave 0 always owns tile 0
  float lsum = l_r * aS;
#pragma unroll
  for (int r = 0; r < 16; ++r) { o0[r] *= aS; o1[r] *= aS; }
#pragma unroll
  for (int pi = 0; pi < 3; ++pi) {
    const float ap = __expf(mlg[pi][0][l] - m);   // zero-tile partner: exp(-inf-m)=0
    lsum += mlg[pi][1][l] * ap;
#pragma unroll
    for (int r = 0; r < 16; ++r) {
      o0[r] += og[pi][r][l] * ap;
      o1[r] += og[pi][16 + r][l] * ap;
    }
  }

  // ---- epilogue: per-lane scalar 1/l, write O[b][q][h*64+d] (row-major for out-GEMM)
  const float inv = 1.0f / lsum;
  u16* op = O + (size_t)b * T_SEQ * D_MOD + (size_t)(q0 + lq) * D_MOD + h * HEAD_DIM;
#pragma unroll
  for (int a = 0; a < 2; ++a) {
#pragma unroll
    for (int rq = 0; rq < 4; ++rq) {
      const int d0 = 32 * a + 8 * rq + 4 * hi;
      ushort4 st;
      st.x = f2bf(((a == 0) ? o0[4 * rq + 0] : o1[4 * rq + 0]) * inv);
      st.y = f2bf(((a == 0) ? o0[4 * rq + 1] : o1[4 * rq + 1]) * inv);
      st.z = f2bf(((a == 0) ? o0[4 * rq + 2] : o1[4 * rq + 2]) * inv);
      st.w = f2bf(((a == 0) ? o0[4 * rq + 3] : o1[4 * rq + 3]) * inv);
      *(ushort4*)(op + d0) = st;
    }
  }
}

// ---------------------------------------------------------------- launch
extern "C" void kernel_launch(void* const* d_in, const int* in_sizes, int n_in,
                              void* d_out, int out_size, void* d_ws, size_t ws_size,
                              hipStream_t stream) {
  const float* x  = (const float*)d_in[0];
  const float* Wq = (const float*)d_in[2];
  const float* bq = (const float*)d_in[3];
  const float* Wk = (const float*)d_in[4];
  const float* bk = (const float*)d_in[5];
  const float* Wv = (const float*)d_in[6];
  const float* bv = (const float*)d_in[7];
  const float* Wo = (const float*)d_in[8];
  const float* bo = (const float*)d_in[9];
  float* out = (float*)d_out;

  char* ws = (char*)d_ws;
  const size_t MB = 1024 * 1024;
  u16* Xb   = (u16*)(ws + 0);          // 8 MB; dead after QKV gemm -> Ab reuses it
  u16* Ab   = (u16*)(ws + 0);
  u16* Wqb  = (u16*)(ws + 8 * MB);
  u16* Wkb  = (u16*)(ws + 10 * MB);
  u16* Wvb  = (u16*)(ws + 12 * MB);
  u16* Wob  = (u16*)(ws + 14 * MB);
  u16* Qb   = (u16*)(ws + 16 * MB);    // 8 MB blocked [bh][dc][t][8]
  u16* Kb   = (u16*)(ws + 24 * MB);    // 8 MB blocked [bh][dc][t][8]
  u16* Vb   = (u16*)(ws + 32 * MB);    // 8 MB blocked [bh][kvc][d][8]
  float* cosT = (float*)(ws + 48 * MB);          // 256 KB
  float* sinT = (float*)(ws + 48 * MB + 256 * 1024);

  cast_all_kernel<<<8192, 256, 0, stream>>>(x, Wq, Wk, Wv, Wo, Xb, Wqb, Wkb, Wvb, Wob);
  rope_table_kernel<<<256, 256, 0, stream>>>(cosT, sinT);

  gemm128_kernel<1, 1><<<dim3(8, 32, 3), 256, 0, stream>>>(
      Xb, Wqb, Wkb, Wvb, bq, bk, bv, Qb, Kb, Vb, cosT, sinT);

  flash8_kernel<<<dim3(2048), 256, 0, stream>>>(Qb, Kb, Vb, Ab);

  gemm128_kernel<0, 0><<<dim3(8, 32, 1), 256, 0, stream>>>(
      Ab, Wob, Wob, Wob, bo, bo, bo, out, out, out, nullptr, nullptr);
}